// Round 3
// baseline (560.954 us; speedup 1.0000x reference)
//
#include <hip/hip_runtime.h>

#define NB 16
#define SEQ 4096
#define DIMC 1024
#define NH 16
#define DH 64
#define NC 64   // 64-row chunks per batch (kS / softmax stats)
#define RS 16   // row-splits for kY (256 rows = 4 chunks per block)

// ws layout (floats):
#define OFF_Q    0            // [16][1024]            16384
#define OFF_WTIL 16384        // [16][16][1024]        262144
#define OFF_PMAX 278528       // [16][64][16]          16384
#define OFF_LC   294912       // [16][64][16]          16384
#define OFF_E    311296       // [16][4096][16]        1048576  (exp(S - m_chunk))
#define OFF_YOUT 1359872      // [16][16][16][1024]    4194304  (row-split partials of phat@x)
#define OFF_HO   5554176      // [16][1024]            16384
// total 5570560 floats = 22.3 MB

// ---------- kq: q[b][j] = x[b,0,:] . Wq[:,j]   (grid 16 jc x 16 b)
__global__ __launch_bounds__(256) void kq(const float* __restrict__ x,
                                          const float* __restrict__ Wq,
                                          float* __restrict__ qws) {
  const int jc = blockIdx.x, b = blockIdx.y, t = threadIdx.x;
  const int d = t & 63, g = t >> 6;
  const int j = jc * 64 + d;
  const float* x0 = x + (size_t)b * SEQ * DIMC;
  __shared__ float red[256];
  float a = 0.f;
  #pragma unroll 8
  for (int c = g * 256; c < g * 256 + 256; ++c)
    a = fmaf(x0[c], Wq[(size_t)c * DIMC + j], a);
  red[t] = a;
  __syncthreads();
  if (t < 64)
    qws[b * DIMC + jc * 64 + t] = red[t] + red[64 + t] + red[128 + t] + red[192 + t];
}

// ---------- kw: wtil[b][h][c] = 0.125 * Wk[c, h*64: h*64+64] . q[b, h*64: h*64+64]
// (RoPE cancels in q_rot . k_rot since both use the same per-head rotation.)
__global__ __launch_bounds__(256) void kw(const float* __restrict__ Wk,
                                          const float* __restrict__ qws,
                                          float* __restrict__ wtil) {
  const int cb = blockIdx.x, b = blockIdx.y, t = threadIdx.x;
  const int w = t >> 6, l = t & 63;
  float4 qreg[4];
  {
    const float4* q4 = (const float4*)(qws + b * DIMC + l * 16);
    #pragma unroll
    for (int i = 0; i < 4; ++i) qreg[i] = q4[i];
  }
  const int h = l >> 2;
  float* wt = wtil + ((size_t)b * NH + h) * DIMC;
  #pragma unroll 4
  for (int i = 0; i < 16; ++i) {
    const int c = cb * 64 + w * 16 + i;
    const float4* row = (const float4*)(Wk + (size_t)c * DIMC) + l * 4;
    float s = 0.f;
    #pragma unroll
    for (int k = 0; k < 4; ++k) {
      float4 rv = row[k];
      s = fmaf(rv.x, qreg[k].x, s); s = fmaf(rv.y, qreg[k].y, s);
      s = fmaf(rv.z, qreg[k].z, s); s = fmaf(rv.w, qreg[k].w, s);
    }
    s += __shfl_xor(s, 1);
    s += __shfl_xor(s, 2);
    if ((l & 3) == 0) wt[c] = s * 0.125f;
  }
}

// ---------- kS: logits + chunk-local softmax stats, reduce-free dot products.
// Block (nc, b). Lane l owns row nc*64+l; wave w owns k-quarter w (256 dims).
// acc[16] = partial dot for all 16 heads. Combine quarters via small LDS transpose.
__global__ __launch_bounds__(256) void kS(const float* __restrict__ x,
                                          const float* __restrict__ wtil,
                                          float* __restrict__ e,
                                          float* __restrict__ pmax,
                                          float* __restrict__ Lc) {
  const int nc = blockIdx.x, b = blockIdx.y, t = threadIdx.x;
  const int w = t >> 6, l = t & 63;
  const int wq = __builtin_amdgcn_readfirstlane(w);  // wave-uniform -> scalar loads for wtil

  const float4* xrow = (const float4*)x + ((size_t)b * SEQ + nc * 64 + l) * 256 + wq * 64;
  const float4* wt   = (const float4*)wtil + ((size_t)b * NH) * 256 + wq * 64;

  float acc[16] = {0.f, 0.f, 0.f, 0.f, 0.f, 0.f, 0.f, 0.f,
                   0.f, 0.f, 0.f, 0.f, 0.f, 0.f, 0.f, 0.f};
  for (int k4 = 0; k4 < 64; k4 += 4) {
    float4 xv[4];
    #pragma unroll
    for (int i = 0; i < 4; ++i) xv[i] = xrow[k4 + i];
    #pragma unroll
    for (int h = 0; h < 16; ++h) {
      #pragma unroll
      for (int i = 0; i < 4; ++i) {
        float4 wv = wt[h * 256 + k4 + i];
        acc[h] = fmaf(xv[i].x, wv.x, acc[h]);
        acc[h] = fmaf(xv[i].y, wv.y, acc[h]);
        acc[h] = fmaf(xv[i].z, wv.z, acc[h]);
        acc[h] = fmaf(xv[i].w, wv.w, acc[h]);
      }
    }
  }

  // combine k-quarters: part[head-quad][k-wave][row]
  __shared__ float4 part[4][4][64];
  #pragma unroll
  for (int q = 0; q < 4; ++q)
    part[q][w][l] = make_float4(acc[4 * q], acc[4 * q + 1], acc[4 * q + 2], acc[4 * q + 3]);
  __syncthreads();

  float4 va;
  {
    float4 p0 = part[w][0][l], p1 = part[w][1][l], p2 = part[w][2][l], p3 = part[w][3][l];
    va.x = (p0.x + p1.x) + (p2.x + p3.x);
    va.y = (p0.y + p1.y) + (p2.y + p3.y);
    va.z = (p0.z + p1.z) + (p2.z + p3.z);
    va.w = (p0.w + p1.w) + (p2.w + p3.w);
  }

  // chunk-local max / exp / sum over rows (lanes), head-quad w
  float4 m4 = va;
  #pragma unroll
  for (int o = 1; o < 64; o <<= 1) {
    m4.x = fmaxf(m4.x, __shfl_xor(m4.x, o)); m4.y = fmaxf(m4.y, __shfl_xor(m4.y, o));
    m4.z = fmaxf(m4.z, __shfl_xor(m4.z, o)); m4.w = fmaxf(m4.w, __shfl_xor(m4.w, o));
  }
  float4 pv;
  pv.x = __expf(va.x - m4.x); pv.y = __expf(va.y - m4.y);
  pv.z = __expf(va.z - m4.z); pv.w = __expf(va.w - m4.w);
  float4 s4 = pv;
  #pragma unroll
  for (int o = 1; o < 64; o <<= 1) {
    s4.x += __shfl_xor(s4.x, o); s4.y += __shfl_xor(s4.y, o);
    s4.z += __shfl_xor(s4.z, o); s4.w += __shfl_xor(s4.w, o);
  }
  ((float4*)e)[((size_t)b * SEQ + nc * 64 + l) * 4 + w] = pv;
  if (l == 0) {
    ((float4*)(pmax + ((size_t)b * NC + nc) * NH))[w] = m4;
    ((float4*)(Lc + ((size_t)b * NC + nc) * NH))[w] = s4;
  }
}

// ---------- kY: global softmax scales + row-split partial of phat @ x.
// Block (rs, b) covers rows rs*256..rs*256+255 (4 chunks). Thread t owns col-quad t
// (256 quads = ALL 1024 cols -> no cross-thread reduction, no write races).
// Per chunk, phat rows staged once into LDS (pre-scaled), broadcast-read in row loop.
__global__ __launch_bounds__(256) void kY(const float* __restrict__ x,
                                          const float* __restrict__ e,
                                          const float* __restrict__ pmax,
                                          const float* __restrict__ Lc,
                                          float* __restrict__ yout) {
  const int rs = blockIdx.x, b = blockIdx.y, t = threadIdx.x;
  __shared__ float4 sc4[NC][4];  // [chunk][head-quad] : exp(m_ch - M)/L
  __shared__ float4 pl[64][4];   // staged phat rows for current chunk

  if (t < 64) {  // wave 0: lane = chunk
    const int ch = t;
    float scl[16];
    #pragma unroll
    for (int h = 0; h < 16; ++h) {
      float m  = pmax[((size_t)b * NC + ch) * NH + h];
      float lc = Lc[((size_t)b * NC + ch) * NH + h];
      float M = m;
      #pragma unroll
      for (int o = 1; o < 64; o <<= 1) M = fmaxf(M, __shfl_xor(M, o));
      float ex = __expf(m - M);
      float lw = lc * ex;
      #pragma unroll
      for (int o = 1; o < 64; o <<= 1) lw += __shfl_xor(lw, o);
      scl[h] = ex / lw;
    }
    #pragma unroll
    for (int q = 0; q < 4; ++q)
      sc4[ch][q] = make_float4(scl[4 * q], scl[4 * q + 1], scl[4 * q + 2], scl[4 * q + 3]);
  }

  const float4* x4 = (const float4*)x + (size_t)b * SEQ * 256;
  const float4* e4 = (const float4*)e + (size_t)b * SEQ * 4;

  float4 acc[16];
  #pragma unroll
  for (int h = 0; h < 16; ++h) acc[h] = make_float4(0.f, 0.f, 0.f, 0.f);

  for (int c4 = 0; c4 < 4; ++c4) {
    const int ch = rs * 4 + c4;
    __syncthreads();  // protect sc4 (first iter) / pl readers (later iters)
    {
      const int r = t >> 2, qd = t & 3;
      float4 ev = e4[(size_t)(ch * 64 + r) * 4 + qd];
      float4 s  = sc4[ch][qd];
      pl[r][qd] = make_float4(ev.x * s.x, ev.y * s.y, ev.z * s.z, ev.w * s.w);
    }
    __syncthreads();

    const float4* xc = x4 + (size_t)(ch * 64) * 256;
    for (int r = 0; r < 64; r += 2) {
      float4 xva = xc[(size_t)r * 256 + t];
      float4 xvb = xc[(size_t)(r + 1) * 256 + t];
      float4 a0 = pl[r][0], a1 = pl[r][1], a2 = pl[r][2], a3 = pl[r][3];
      float4 b0 = pl[r + 1][0], b1 = pl[r + 1][1], b2 = pl[r + 1][2], b3 = pl[r + 1][3];
      #define ACC(h, ev, xv) acc[h].x = fmaf(ev, xv.x, acc[h].x); acc[h].y = fmaf(ev, xv.y, acc[h].y); \
                             acc[h].z = fmaf(ev, xv.z, acc[h].z); acc[h].w = fmaf(ev, xv.w, acc[h].w)
      ACC(0, a0.x, xva); ACC(1, a0.y, xva); ACC(2, a0.z, xva); ACC(3, a0.w, xva);
      ACC(4, a1.x, xva); ACC(5, a1.y, xva); ACC(6, a1.z, xva); ACC(7, a1.w, xva);
      ACC(8, a2.x, xva); ACC(9, a2.y, xva); ACC(10, a2.z, xva); ACC(11, a2.w, xva);
      ACC(12, a3.x, xva); ACC(13, a3.y, xva); ACC(14, a3.z, xva); ACC(15, a3.w, xva);
      ACC(0, b0.x, xvb); ACC(1, b0.y, xvb); ACC(2, b0.z, xvb); ACC(3, b0.w, xvb);
      ACC(4, b1.x, xvb); ACC(5, b1.y, xvb); ACC(6, b1.z, xvb); ACC(7, b1.w, xvb);
      ACC(8, b2.x, xvb); ACC(9, b2.y, xvb); ACC(10, b2.z, xvb); ACC(11, b2.w, xvb);
      ACC(12, b3.x, xvb); ACC(13, b3.y, xvb); ACC(14, b3.z, xvb); ACC(15, b3.w, xvb);
      #undef ACC
    }
  }

  float4* yo = (float4*)yout + (((size_t)b * RS + rs) * NH) * 256 + t;
  #pragma unroll
  for (int h = 0; h < 16; ++h) yo[h * 256] = acc[h];
}

// ---------- kV: ho[b][h*64+d] = (sum_rs yout[b][rs][h][:]) . Wv[:, h*64+d]
__global__ __launch_bounds__(256) void kV(const float* __restrict__ yout,
                                          const float* __restrict__ Wv,
                                          float* __restrict__ ho) {
  const int cq = blockIdx.x, h = blockIdx.y, b = blockIdx.z, t = threadIdx.x;
  __shared__ float ysum[DIMC];
  __shared__ float red[256];
  #pragma unroll
  for (int i = 0; i < 4; ++i) {
    const int c = i * 256 + t;
    float s = 0.f;
    #pragma unroll
    for (int r = 0; r < RS; ++r)
      s += yout[(((size_t)b * RS + r) * NH + h) * DIMC + c];
    ysum[c] = s;
  }
  __syncthreads();
  const int d = t & 15, g = t >> 4;
  float a = 0.f;
  #pragma unroll 8
  for (int i = 0; i < 64; ++i)
    a = fmaf(ysum[g * 64 + i], Wv[(size_t)(g * 64 + i) * DIMC + h * DH + cq * 16 + d], a);
  red[t] = a;
  __syncthreads();
  if (t < 16) {
    float s = 0.f;
    #pragma unroll
    for (int j = 0; j < 16; ++j) s += red[j * 16 + t];
    ho[(size_t)b * DIMC + h * DH + cq * 16 + t] = s;
  }
}

// ---------- k_out: out[b, j] = ho[b,:] . Wp[:, j] + bp[j]
__global__ __launch_bounds__(256) void k_out(const float* __restrict__ ho,
                                             const float* __restrict__ Wp,
                                             const float* __restrict__ bp,
                                             float* __restrict__ out) {
  const int jc = blockIdx.x, b = blockIdx.y, t = threadIdx.x;
  __shared__ float hs[1024];
  __shared__ float red[256];
  for (int i = t; i < 1024; i += 256)
    hs[i] = ho[(size_t)b * DIMC + i];
  __syncthreads();
  const int d = t & 63, g = t >> 6;
  const int j = jc * 64 + d;
  float a = 0.f;
  #pragma unroll 8
  for (int i = g * 256; i < g * 256 + 256; ++i)
    a = fmaf(hs[i], Wp[(size_t)i * DIMC + j], a);
  red[t] = a;
  __syncthreads();
  if (t < 64)
    out[(size_t)b * DIMC + jc * 64 + t] =
        red[t] + red[64 + t] + red[128 + t] + red[192 + t] + bp[jc * 64 + t];
}

extern "C" void kernel_launch(void* const* d_in, const int* in_sizes, int n_in,
                              void* d_out, int out_size, void* d_ws, size_t ws_size,
                              hipStream_t stream) {
  const float* x  = (const float*)d_in[0];
  const float* Wq = (const float*)d_in[1];
  const float* Wk = (const float*)d_in[2];
  const float* Wv = (const float*)d_in[3];
  const float* Wp = (const float*)d_in[4];
  const float* bp = (const float*)d_in[5];
  float* out = (float*)d_out;
  float* ws = (float*)d_ws;

  float* qws  = ws + OFF_Q;
  float* wtil = ws + OFF_WTIL;
  float* pmax = ws + OFF_PMAX;
  float* Lc   = ws + OFF_LC;
  float* e    = ws + OFF_E;
  float* yout = ws + OFF_YOUT;
  float* ho   = ws + OFF_HO;

  kq<<<dim3(16, NB), 256, 0, stream>>>(x, Wq, qws);
  kw<<<dim3(16, NB), 256, 0, stream>>>(Wk, qws, wtil);
  kS<<<dim3(NC, NB), 256, 0, stream>>>(x, wtil, e, pmax, Lc);
  kY<<<dim3(RS, NB), 256, 0, stream>>>(x, e, pmax, Lc, yout);
  kV<<<dim3(4, NH, NB), 256, 0, stream>>>(yout, Wv, ho);
  k_out<<<dim3(16, NB), 256, 0, stream>>>(ho, Wp, bp, out);
}

// Round 5
// 527.078 us; speedup vs baseline: 1.0643x; 1.0643x over previous
//
#include <hip/hip_runtime.h>

#define NB 16
#define SEQ 4096
#define DIMC 1024
#define NH 16
#define DH 64
#define NC 64   // 64-row chunks per batch (kS / softmax stats)
#define RS 32   // row-splits for kY (128 rows = 2 chunks per block) -> 512 blocks = 2/CU

// ws layout (floats):
#define OFF_Q    0            // [16][1024]            16384
#define OFF_WTIL 16384        // [16][16][1024]        262144
#define OFF_PMAX 278528       // [16][64][16]          16384
#define OFF_LC   294912       // [16][64][16]          16384
#define OFF_E    311296       // [16][4096][16]        1048576  (exp(S - m_chunk))
#define OFF_YOUT 1359872      // [16][32][16][1024]    8388608  (row-split partials of phat@x)
#define OFF_HO   9748480      // [16][1024]            16384
// total 9764864 floats = 39.1 MB

// ---------- kq: q[b][j] = x[b,0,:] . Wq[:,j]   (grid 16 jc x 16 b)
__global__ __launch_bounds__(256) void kq(const float* __restrict__ x,
                                          const float* __restrict__ Wq,
                                          float* __restrict__ qws) {
  const int jc = blockIdx.x, b = blockIdx.y, t = threadIdx.x;
  const int d = t & 63, g = t >> 6;
  const int j = jc * 64 + d;
  const float* x0 = x + (size_t)b * SEQ * DIMC;
  __shared__ float red[256];
  float a = 0.f;
  #pragma unroll 8
  for (int c = g * 256; c < g * 256 + 256; ++c)
    a = fmaf(x0[c], Wq[(size_t)c * DIMC + j], a);
  red[t] = a;
  __syncthreads();
  if (t < 64)
    qws[b * DIMC + jc * 64 + t] = red[t] + red[64 + t] + red[128 + t] + red[192 + t];
}

// ---------- kw: wtil[b][h][c] = 0.125 * Wk[c, h*64: h*64+64] . q[b, h*64: h*64+64]
// (RoPE cancels in q_rot . k_rot since both use the same per-head rotation.)
__global__ __launch_bounds__(256) void kw(const float* __restrict__ Wk,
                                          const float* __restrict__ qws,
                                          float* __restrict__ wtil) {
  const int cb = blockIdx.x, b = blockIdx.y, t = threadIdx.x;
  const int w = t >> 6, l = t & 63;
  float4 qreg[4];
  {
    const float4* q4 = (const float4*)(qws + b * DIMC + l * 16);
    #pragma unroll
    for (int i = 0; i < 4; ++i) qreg[i] = q4[i];
  }
  const int h = l >> 2;
  float* wt = wtil + ((size_t)b * NH + h) * DIMC;
  #pragma unroll 4
  for (int i = 0; i < 16; ++i) {
    const int c = cb * 64 + w * 16 + i;
    const float4* row = (const float4*)(Wk + (size_t)c * DIMC) + l * 4;
    float s = 0.f;
    #pragma unroll
    for (int k = 0; k < 4; ++k) {
      float4 rv = row[k];
      s = fmaf(rv.x, qreg[k].x, s); s = fmaf(rv.y, qreg[k].y, s);
      s = fmaf(rv.z, qreg[k].z, s); s = fmaf(rv.w, qreg[k].w, s);
    }
    s += __shfl_xor(s, 1);
    s += __shfl_xor(s, 2);
    if ((l & 3) == 0) wt[c] = s * 0.125f;
  }
}

__device__ __forceinline__ float dot16(const float4* xv, const float4* wv) {
  float s = 0.f;
  #pragma unroll
  for (int i = 0; i < 4; ++i) {
    s = fmaf(xv[i].x, wv[i].x, s); s = fmaf(xv[i].y, wv[i].y, s);
    s = fmaf(xv[i].z, wv[i].z, s); s = fmaf(xv[i].w, wv[i].w, s);
  }
  return s;
}

// ---------- kS: logits + chunk-local softmax stats (old proven coalesced pattern).
// Block (nc, b). Wave w -> heads 4w..4w+3; lane l owns column-quads {l, 64+l, 128+l, 192+l};
// butterfly reduce across lanes; lane r captures row r. Writes e = exp(S - m_chunk) + stats.
__global__ __launch_bounds__(256) void kS(const float* __restrict__ x,
                                          const float* __restrict__ wtil,
                                          float* __restrict__ e,
                                          float* __restrict__ pmax,
                                          float* __restrict__ Lc) {
  const int nc = blockIdx.x, b = blockIdx.y, t = threadIdx.x;
  const int w = t >> 6, l = t & 63;

  const float4* wt4 = (const float4*)wtil + ((size_t)b * NH + w * 4) * 256;
  float4 wv[4][4];
  #pragma unroll
  for (int h = 0; h < 4; ++h)
    #pragma unroll
    for (int i = 0; i < 4; ++i) wv[h][i] = wt4[h * 256 + i * 64 + l];
  const float4* x4 = (const float4*)x + ((size_t)b * SEQ + nc * 64) * 256;
  float4 va = make_float4(0.f, 0.f, 0.f, 0.f);

  for (int r = 0; r < 64; r += 2) {
    float4 xa[4], xb[4];
    #pragma unroll
    for (int i = 0; i < 4; ++i) xa[i] = x4[r * 256 + i * 64 + l];
    #pragma unroll
    for (int i = 0; i < 4; ++i) xb[i] = x4[(r + 1) * 256 + i * 64 + l];
    float4 sa, sb;
    sa.x = dot16(xa, wv[0]); sa.y = dot16(xa, wv[1]);
    sa.z = dot16(xa, wv[2]); sa.w = dot16(xa, wv[3]);
    sb.x = dot16(xb, wv[0]); sb.y = dot16(xb, wv[1]);
    sb.z = dot16(xb, wv[2]); sb.w = dot16(xb, wv[3]);
    #pragma unroll
    for (int o = 1; o < 64; o <<= 1) {
      sa.x += __shfl_xor(sa.x, o); sa.y += __shfl_xor(sa.y, o);
      sa.z += __shfl_xor(sa.z, o); sa.w += __shfl_xor(sa.w, o);
      sb.x += __shfl_xor(sb.x, o); sb.y += __shfl_xor(sb.y, o);
      sb.z += __shfl_xor(sb.z, o); sb.w += __shfl_xor(sb.w, o);
    }
    if (l == r) va = sa;
    if (l == r + 1) va = sb;
  }

  // chunk-local max / exp / sum over rows (lanes), head-quad w
  float4 m4 = va;
  #pragma unroll
  for (int o = 1; o < 64; o <<= 1) {
    m4.x = fmaxf(m4.x, __shfl_xor(m4.x, o)); m4.y = fmaxf(m4.y, __shfl_xor(m4.y, o));
    m4.z = fmaxf(m4.z, __shfl_xor(m4.z, o)); m4.w = fmaxf(m4.w, __shfl_xor(m4.w, o));
  }
  float4 pv;
  pv.x = __expf(va.x - m4.x); pv.y = __expf(va.y - m4.y);
  pv.z = __expf(va.z - m4.z); pv.w = __expf(va.w - m4.w);
  float4 s4 = pv;
  #pragma unroll
  for (int o = 1; o < 64; o <<= 1) {
    s4.x += __shfl_xor(s4.x, o); s4.y += __shfl_xor(s4.y, o);
    s4.z += __shfl_xor(s4.z, o); s4.w += __shfl_xor(s4.w, o);
  }
  ((float4*)e)[((size_t)b * SEQ + nc * 64 + l) * 4 + w] = pv;
  if (l == 0) {
    ((float4*)(pmax + ((size_t)b * NC + nc) * NH))[w] = m4;
    ((float4*)(Lc + ((size_t)b * NC + nc) * NH))[w] = s4;
  }
}

// ---------- kY: global softmax scales + row-split partial of phat @ x.
// Block (rs, b) covers rows rs*128..rs*128+127 (2 chunks). Thread t owns col-quad t
// (256 quads = ALL 1024 cols -> no cross-thread reduction, no write races).
// 512 blocks = 2 blocks/CU; 4-row unroll = 4 independent x loads in flight.
__global__ __launch_bounds__(256) void kY(const float* __restrict__ x,
                                          const float* __restrict__ e,
                                          const float* __restrict__ pmax,
                                          const float* __restrict__ Lc,
                                          float* __restrict__ yout) {
  const int rs = blockIdx.x, b = blockIdx.y, t = threadIdx.x;
  __shared__ float4 sc4[NC][4];  // [chunk][head-quad] : exp(m_ch - M)/L
  __shared__ float4 pl[64][4];   // staged phat rows for current chunk

  if (t < 64) {  // wave 0: lane = chunk
    const int ch = t;
    float scl[16];
    #pragma unroll
    for (int h = 0; h < 16; ++h) {
      float m  = pmax[((size_t)b * NC + ch) * NH + h];
      float lc = Lc[((size_t)b * NC + ch) * NH + h];
      float M = m;
      #pragma unroll
      for (int o = 1; o < 64; o <<= 1) M = fmaxf(M, __shfl_xor(M, o));
      float ex = __expf(m - M);
      float lw = lc * ex;
      #pragma unroll
      for (int o = 1; o < 64; o <<= 1) lw += __shfl_xor(lw, o);
      scl[h] = ex / lw;
    }
    #pragma unroll
    for (int q = 0; q < 4; ++q)
      sc4[ch][q] = make_float4(scl[4 * q], scl[4 * q + 1], scl[4 * q + 2], scl[4 * q + 3]);
  }

  const float4* x4 = (const float4*)x + (size_t)b * SEQ * 256;
  const float4* e4 = (const float4*)e + (size_t)b * SEQ * 4;

  float4 acc[16];
  #pragma unroll
  for (int h = 0; h < 16; ++h) acc[h] = make_float4(0.f, 0.f, 0.f, 0.f);

  for (int c4 = 0; c4 < 2; ++c4) {
    const int ch = rs * 2 + c4;
    __syncthreads();  // protect sc4 (first iter) / pl readers (later iters)
    {
      const int r = t >> 2, qd = t & 3;
      float4 ev = e4[(size_t)(ch * 64 + r) * 4 + qd];
      float4 s  = sc4[ch][qd];
      pl[r][qd] = make_float4(ev.x * s.x, ev.y * s.y, ev.z * s.z, ev.w * s.w);
    }
    __syncthreads();

    const float4* xc = x4 + (size_t)(ch * 64) * 256;
    for (int r = 0; r < 64; r += 4) {
      float4 xv0 = xc[(size_t)(r + 0) * 256 + t];
      float4 xv1 = xc[(size_t)(r + 1) * 256 + t];
      float4 xv2 = xc[(size_t)(r + 2) * 256 + t];
      float4 xv3 = xc[(size_t)(r + 3) * 256 + t];
      #pragma unroll
      for (int rr = 0; rr < 4; ++rr) {
        float4 xv = (rr == 0) ? xv0 : (rr == 1) ? xv1 : (rr == 2) ? xv2 : xv3;
        float4 p0 = pl[r + rr][0], p1 = pl[r + rr][1];
        float4 p2 = pl[r + rr][2], p3 = pl[r + rr][3];
        #define ACC(h, ev) acc[h].x = fmaf(ev, xv.x, acc[h].x); acc[h].y = fmaf(ev, xv.y, acc[h].y); \
                           acc[h].z = fmaf(ev, xv.z, acc[h].z); acc[h].w = fmaf(ev, xv.w, acc[h].w)
        ACC(0, p0.x); ACC(1, p0.y); ACC(2, p0.z); ACC(3, p0.w);
        ACC(4, p1.x); ACC(5, p1.y); ACC(6, p1.z); ACC(7, p1.w);
        ACC(8, p2.x); ACC(9, p2.y); ACC(10, p2.z); ACC(11, p2.w);
        ACC(12, p3.x); ACC(13, p3.y); ACC(14, p3.z); ACC(15, p3.w);
        #undef ACC
      }
    }
  }

  float4* yo = (float4*)yout + (((size_t)b * RS + rs) * NH) * 256 + t;
  #pragma unroll
  for (int h = 0; h < 16; ++h) yo[h * 256] = acc[h];
}

// ---------- kV: ho[b][h*64+d] = (sum_rs yout[b][rs][h][:]) . Wv[:, h*64+d]
__global__ __launch_bounds__(256) void kV(const float* __restrict__ yout,
                                          const float* __restrict__ Wv,
                                          float* __restrict__ ho) {
  const int cq = blockIdx.x, h = blockIdx.y, b = blockIdx.z, t = threadIdx.x;
  __shared__ float ysum[DIMC];
  __shared__ float red[256];
  #pragma unroll
  for (int i = 0; i < 4; ++i) {
    const int c = i * 256 + t;
    float s = 0.f;
    #pragma unroll 8
    for (int r = 0; r < RS; ++r)
      s += yout[(((size_t)b * RS + r) * NH + h) * DIMC + c];
    ysum[c] = s;
  }
  __syncthreads();
  const int d = t & 15, g = t >> 4;
  float a = 0.f;
  #pragma unroll 8
  for (int i = 0; i < 64; ++i)
    a = fmaf(ysum[g * 64 + i], Wv[(size_t)(g * 64 + i) * DIMC + h * DH + cq * 16 + d], a);
  red[t] = a;
  __syncthreads();
  if (t < 16) {
    float s = 0.f;
    #pragma unroll
    for (int j = 0; j < 16; ++j) s += red[j * 16 + t];
    ho[(size_t)b * DIMC + h * DH + cq * 16 + t] = s;
  }
}

// ---------- k_out: out[b, j] = ho[b,:] . Wp[:, j] + bp[j]
__global__ __launch_bounds__(256) void k_out(const float* __restrict__ ho,
                                             const float* __restrict__ Wp,
                                             const float* __restrict__ bp,
                                             float* __restrict__ out) {
  const int jc = blockIdx.x, b = blockIdx.y, t = threadIdx.x;
  __shared__ float hs[1024];
  __shared__ float red[256];
  for (int i = t; i < 1024; i += 256)
    hs[i] = ho[(size_t)b * DIMC + i];
  __syncthreads();
  const int d = t & 63, g = t >> 6;
  const int j = jc * 64 + d;
  float a = 0.f;
  #pragma unroll 8
  for (int i = g * 256; i < g * 256 + 256; ++i)
    a = fmaf(hs[i], Wp[(size_t)i * DIMC + j], a);
  red[t] = a;
  __syncthreads();
  if (t < 64)
    out[(size_t)b * DIMC + jc * 64 + t] =
        red[t] + red[64 + t] + red[128 + t] + red[192 + t] + bp[jc * 64 + t];
}

extern "C" void kernel_launch(void* const* d_in, const int* in_sizes, int n_in,
                              void* d_out, int out_size, void* d_ws, size_t ws_size,
                              hipStream_t stream) {
  const float* x  = (const float*)d_in[0];
  const float* Wq = (const float*)d_in[1];
  const float* Wk = (const float*)d_in[2];
  const float* Wv = (const float*)d_in[3];
  const float* Wp = (const float*)d_in[4];
  const float* bp = (const float*)d_in[5];
  float* out = (float*)d_out;
  float* ws = (float*)d_ws;

  float* qws  = ws + OFF_Q;
  float* wtil = ws + OFF_WTIL;
  float* pmax = ws + OFF_PMAX;
  float* Lc   = ws + OFF_LC;
  float* e    = ws + OFF_E;
  float* yout = ws + OFF_YOUT;
  float* ho   = ws + OFF_HO;

  kq<<<dim3(16, NB), 256, 0, stream>>>(x, Wq, qws);
  kw<<<dim3(16, NB), 256, 0, stream>>>(Wk, qws, wtil);
  kS<<<dim3(NC, NB), 256, 0, stream>>>(x, wtil, e, pmax, Lc);
  kY<<<dim3(RS, NB), 256, 0, stream>>>(x, e, pmax, Lc, yout);
  kV<<<dim3(4, NH, NB), 256, 0, stream>>>(yout, Wv, ho);
  k_out<<<dim3(16, NB), 256, 0, stream>>>(ho, Wp, bp, out);
}